// Round 9
// baseline (117.698 us; speedup 1.0000x reference)
//
#include <hip/hip_runtime.h>
#include <hip/hip_fp16.h>

#define CH 16
#define HH 512
#define WW 960
#define HW (HH * WW)

#define TR 8      // output rows per block
#define TC 64     // output cols per block
#define RROWS 18  // staged rows [y0b-9, y0b+8]
#define RCOLS 136 // staged cols [x0b-68, x0b+67]
#define NSLOT (RROWS * RCOLS)  // 2448 slots: one uint4 (8 ch f16) per pixel

typedef __fp16 v2hf __attribute__((ext_vector_type(2)));   // builtin's type
typedef _Float16 h2r __attribute__((ext_vector_type(2)));  // arithmetic type

__device__ __forceinline__ unsigned pkrtz_u(float a, float b) {
  v2hf r = __builtin_amdgcn_cvt_pkrtz(a, b);
  return __builtin_bit_cast(unsigned, r);
}
__device__ __forceinline__ __half2 u2h(unsigned u) {
  return __builtin_bit_cast(__half2, u);
}

// LDS-only workgroup barrier: waits ds ops (lgkmcnt) but does NOT drain
// vmcnt -> in-flight global stores / loads stay outstanding across it.
#define LBAR() asm volatile("s_waitcnt lgkmcnt(0)\n\ts_barrier" ::: "memory")

// ---------------------------------------------------------------------------
// Fused, chunk-split two-pass with T14 async staging:
//   setup (hoisted)  -> stage0 (load+pack+ds_write)
//   issue+pack chunk1 loads into 20 held VGPRs   <- latency overlaps gather0
//   LBAR -> gather0+store ch0-7 -> LBAR -> ds_write chunk1 -> LBAR
//   gather1+store ch8-15
// ---------------------------------------------------------------------------
__global__ __launch_bounds__(512, 6) void recon_fused_f16(
    const float* __restrict__ img,   // [16][512][960] f32
    const float* __restrict__ offx,  // [512][960]
    const float* __restrict__ offy,  // [512][960]
    float* __restrict__ out) {       // [16][512][960]
  __shared__ uint4 lds[NSLOT];  // 39168 B

  // XCD swizzle: 960 blocks = 8 XCDs x 120; XCD k owns a 64-row band.
  const int hwid = blockIdx.x + blockIdx.y * 15;
  const int tile = (hwid & 7) * 120 + (hwid >> 3);
  const int tx = tile % 15, ty = tile / 15;
  const int x0b = tx * TC, y0b = ty * TR;
  const int tid = threadIdx.x;
  const int ylo = y0b - 9, xlo = x0b - 68;

  const int pixl = tid & 63;
  const int rowl = tid >> 6;  // 0..7
  const int x = x0b + pixl;
  const int y = y0b + rowl;
  const int po = y * WW + x;

  const float fxs = (float)(WW - 1) / (float)WW;
  const float fys = (float)(HH - 1) / (float)HH;
  const float s = 1.0f / 9.0f;

  // ---------------- hoisted per-neighbor setup (done ONCE) ----------------
  int u00a[9];      // LDS slot index of corner (x0,y0)
  __half2 wxa[9];   // packed (w00, w10)
  __half2 wya[9];   // packed (w01, w11)
#pragma unroll
  for (int di = -1; di <= 1; ++di) {
    int rr = y + di;
    rr = (rr < 0) ? 1 : ((rr >= HH) ? (HH - 2) : rr);  // reflect pad=1
#pragma unroll
    for (int dj = -1; dj <= 1; ++dj) {
      const int n = (di + 1) * 3 + (dj + 1);
      int cc = x + dj;
      cc = (cc < 0) ? 1 : ((cc >= WW) ? (WW - 2) : cc);
      const int o = rr * WW + cc;
      const float sx = offx[o];
      const float sy = offy[o];
      const float cx = fminf(fmaxf((float)x - sx, 0.0f), (float)(WW - 1));
      const float cy = fminf(fmaxf((float)y - sy, 0.0f), (float)(HH - 1));
      const float ix = cx * fxs;  // [0, W-1): x1 stays inside the patch
      const float iy = cy * fys;
      const float fx0 = floorf(ix);
      const float fy0 = floorf(iy);
      const float wx1 = ix - fx0, wx0 = 1.0f - wx1;
      const float wy1 = iy - fy0, wy0 = 1.0f - wy1;
      u00a[n] = ((int)fy0 - ylo) * RCOLS + ((int)fx0 - xlo);
      wxa[n] = u2h(pkrtz_u(wx0 * wy0, wx1 * wy0));  // (w00, w10)
      wya[n] = u2h(pkrtz_u(wx0 * wy1, wx1 * wy1));  // (w01, w11)
    }
  }

  // ---------------- stage chunk0 directly to LDS ----------------
#pragma unroll
  for (int it = 0; it < 5; ++it) {
    const int f = it * 512 + tid;
    if (f < NSLOT) {
      const int row = f / RCOLS;
      const int col = f - row * RCOLS;
      const int gr = min(max(ylo + row, 0), HH - 1);
      const int gc = min(max(xlo + col, 0), WW - 1);
      const float* src = img + gr * WW + gc;  // channels 0..7
      uint4 o;
      o.x = pkrtz_u(src[0 * HW], src[1 * HW]);
      o.y = pkrtz_u(src[2 * HW], src[3 * HW]);
      o.z = pkrtz_u(src[4 * HW], src[5 * HW]);
      o.w = pkrtz_u(src[6 * HW], src[7 * HW]);
      lds[f] = o;
    }
  }

  // ---------------- issue + pack chunk1 stage loads (held in VGPRs) -------
  uint4 p1[5];
#pragma unroll
  for (int it = 0; it < 5; ++it) {
    const int f = it * 512 + tid;
    if (f < NSLOT) {
      const int row = f / RCOLS;
      const int col = f - row * RCOLS;
      const int gr = min(max(ylo + row, 0), HH - 1);
      const int gc = min(max(xlo + col, 0), WW - 1);
      const float* src = img + 8 * HW + gr * WW + gc;  // channels 8..15
      p1[it].x = pkrtz_u(src[0 * HW], src[1 * HW]);
      p1[it].y = pkrtz_u(src[2 * HW], src[3 * HW]);
      p1[it].z = pkrtz_u(src[4 * HW], src[5 * HW]);
      p1[it].w = pkrtz_u(src[6 * HW], src[7 * HW]);
    }
  }

  // ---------------- gather + blend (shared for both chunks) ----------------
  auto gather_store = [&](int cbase) {
    float acc[8];
#pragma unroll
    for (int i = 0; i < 8; ++i) acc[i] = 0.f;
#pragma unroll
    for (int g = 0; g < 3; ++g) {
      __half2 h[4];  // packed partial, <=3 neighbors before f32 fold
#pragma unroll
      for (int i = 0; i < 4; ++i) h[i] = u2h(0u);
#pragma unroll
      for (int dj = 0; dj < 3; ++dj) {
        const int n = g * 3 + dj;
        const int u00 = u00a[n];
        const __half2 w00 = __half2half2(__low2half(wxa[n]));
        const __half2 w10 = __half2half2(__high2half(wxa[n]));
        const __half2 w01 = __half2half2(__low2half(wya[n]));
        const __half2 w11 = __half2half2(__high2half(wya[n]));
#define CORNER(UIDX, Wh)                          \
  {                                               \
    const uint4 q = lds[(UIDX)];                  \
    h[0] = __hfma2(u2h(q.x), (Wh), h[0]);         \
    h[1] = __hfma2(u2h(q.y), (Wh), h[1]);         \
    h[2] = __hfma2(u2h(q.z), (Wh), h[2]);         \
    h[3] = __hfma2(u2h(q.w), (Wh), h[3]);         \
  }
        CORNER(u00, w00)
        CORNER(u00 + 1, w10)
        CORNER(u00 + RCOLS, w01)
        CORNER(u00 + RCOLS + 1, w11)
#undef CORNER
      }
#pragma unroll
      for (int i = 0; i < 4; ++i) {
        const h2r a = __builtin_bit_cast(h2r, h[i]);
        acc[2 * i]     += (float)a.x;
        acc[2 * i + 1] += (float)a.y;
      }
    }
#pragma unroll
    for (int j = 0; j < 8; ++j) out[(cbase + j) * HW + po] = acc[j] * s;
  };

  LBAR();             // chunk0 writes visible
  gather_store(0);    // channels 0..7 (chunk1 loads in flight underneath)
  LBAR();             // all waves done reading chunk0

#pragma unroll
  for (int it = 0; it < 5; ++it) {
    const int f = it * 512 + tid;
    if (f < NSLOT) lds[f] = p1[it];
  }
  LBAR();             // chunk1 writes visible
  gather_store(8);    // channels 8..15
}

extern "C" void kernel_launch(void* const* d_in, const int* in_sizes, int n_in,
                              void* d_out, int out_size, void* d_ws, size_t ws_size,
                              hipStream_t stream) {
  const float* right = (const float*)d_in[0];  // [1,16,512,960]
  const float* offx  = (const float*)d_in[1];  // [1,1,512,960]
  const float* offy  = (const float*)d_in[2];  // [1,1,512,960]
  float* out = (float*)d_out;

  const dim3 grid(WW / TC, HH / TR);  // 15 x 64 = 960 blocks
  recon_fused_f16<<<grid, 512, 0, stream>>>(right, offx, offy, out);
}

// Round 10
// 110.914 us; speedup vs baseline: 1.0612x; 1.0612x over previous
//
#include <hip/hip_runtime.h>
#include <hip/hip_fp16.h>

#define CH 16
#define HH 512
#define WW 960
#define HW (HH * WW)

#define TR 8      // output rows per block
#define TC 64     // output cols per block
#define RROWS 18  // staged rows [y0b-9, y0b+8]
#define RCOLS 136 // staged cols [x0b-68, x0b+67]
#define NSLOT (RROWS * RCOLS)  // 2448 slots: one uint4 (8 ch f16) per pixel

typedef __fp16 v2hf __attribute__((ext_vector_type(2)));   // builtin's type
typedef _Float16 h2r __attribute__((ext_vector_type(2)));  // arithmetic type

__device__ __forceinline__ unsigned pkrtz_u(float a, float b) {
  v2hf r = __builtin_amdgcn_cvt_pkrtz(a, b);
  return __builtin_bit_cast(unsigned, r);
}
__device__ __forceinline__ __half2 u2h(unsigned u) {
  return __builtin_bit_cast(__half2, u);
}

// LDS-only workgroup barrier: waits ds ops (lgkmcnt) but does NOT drain
// vmcnt -> in-flight global loads/stores stay outstanding across it.
#define LBAR() asm volatile("s_waitcnt lgkmcnt(0)\n\ts_barrier" ::: "memory")

// ---------------------------------------------------------------------------
// Fused, double-buffered:
//   setup (hoisted) -> stage0 -> ISSUE chunk1 loads (raw, no pack)
//   LBAR -> gather0 + store ch0-7           <- chunk1 load latency hides here
//   sched_barrier -> vm-wait + pack + ds_write buf1
//   LBAR -> gather1 + store ch8-15
// Block = 8 rows x 64 cols = 512 thr, thread = one output pixel.
// LDS = 2 x 39168 B (static 78336 B, 2 blocks/CU).
// ---------------------------------------------------------------------------
__global__ __launch_bounds__(512, 4) void recon_fused_f16(
    const float* __restrict__ img,   // [16][512][960] f32
    const float* __restrict__ offx,  // [512][960]
    const float* __restrict__ offy,  // [512][960]
    float* __restrict__ out) {       // [16][512][960]
  __shared__ uint4 lds[2][NSLOT];  // 78336 B

  // XCD swizzle: 960 blocks = 8 XCDs x 120; XCD k owns a 64-row band.
  const int hwid = blockIdx.x + blockIdx.y * 15;
  const int tile = (hwid & 7) * 120 + (hwid >> 3);
  const int tx = tile % 15, ty = tile / 15;
  const int x0b = tx * TC, y0b = ty * TR;
  const int tid = threadIdx.x;
  const int ylo = y0b - 9, xlo = x0b - 68;

  const int pixl = tid & 63;
  const int rowl = tid >> 6;  // 0..7
  const int x = x0b + pixl;
  const int y = y0b + rowl;
  const int po = y * WW + x;

  const float fxs = (float)(WW - 1) / (float)WW;
  const float fys = (float)(HH - 1) / (float)HH;
  const float s = 1.0f / 9.0f;

  // ---------------- hoisted per-neighbor setup (done ONCE) ----------------
  int u00a[9];      // LDS slot index of corner (x0,y0)
  __half2 wxa[9];   // packed (w00, w10)
  __half2 wya[9];   // packed (w01, w11)
#pragma unroll
  for (int di = -1; di <= 1; ++di) {
    int rr = y + di;
    rr = (rr < 0) ? 1 : ((rr >= HH) ? (HH - 2) : rr);  // reflect pad=1
#pragma unroll
    for (int dj = -1; dj <= 1; ++dj) {
      const int n = (di + 1) * 3 + (dj + 1);
      int cc = x + dj;
      cc = (cc < 0) ? 1 : ((cc >= WW) ? (WW - 2) : cc);
      const int o = rr * WW + cc;
      const float sx = offx[o];
      const float sy = offy[o];
      const float cx = fminf(fmaxf((float)x - sx, 0.0f), (float)(WW - 1));
      const float cy = fminf(fmaxf((float)y - sy, 0.0f), (float)(HH - 1));
      const float ix = cx * fxs;  // [0, W-1): x1 stays inside the patch
      const float iy = cy * fys;
      const float fx0 = floorf(ix);
      const float fy0 = floorf(iy);
      const float wx1 = ix - fx0, wx0 = 1.0f - wx1;
      const float wy1 = iy - fy0, wy0 = 1.0f - wy1;
      u00a[n] = ((int)fy0 - ylo) * RCOLS + ((int)fx0 - xlo);
      wxa[n] = u2h(pkrtz_u(wx0 * wy0, wx1 * wy0));  // (w00, w10)
      wya[n] = u2h(pkrtz_u(wx0 * wy1, wx1 * wy1));  // (w01, w11)
    }
  }

  // staging geometry (shared by both chunks)
  int sgr[5], sgc[5];
#pragma unroll
  for (int it = 0; it < 5; ++it) {
    const int f = it * 512 + tid;
    const int fc = (f < NSLOT) ? f : (NSLOT - 1);
    const int row = fc / RCOLS;
    const int col = fc - row * RCOLS;
    sgr[it] = min(max(ylo + row, 0), HH - 1);
    sgc[it] = min(max(xlo + col, 0), WW - 1);
  }

  // ---------------- stage chunk0 (ch 0..7) into buf0 ----------------
#pragma unroll
  for (int it = 0; it < 5; ++it) {
    const int f = it * 512 + tid;
    if (f < NSLOT) {
      const float* src = img + sgr[it] * WW + sgc[it];
      uint4 o;
      o.x = pkrtz_u(src[0 * HW], src[1 * HW]);
      o.y = pkrtz_u(src[2 * HW], src[3 * HW]);
      o.z = pkrtz_u(src[4 * HW], src[5 * HW]);
      o.w = pkrtz_u(src[6 * HW], src[7 * HW]);
      lds[0][f] = o;
    }
  }

  // ---------------- ISSUE chunk1 loads raw (no pack -> no vm-wait yet) ----
  float r1[5][8];
#pragma unroll
  for (int it = 0; it < 5; ++it) {
    const float* src = img + 8 * HW + sgr[it] * WW + sgc[it];
#pragma unroll
    for (int k = 0; k < 8; ++k) r1[it][k] = src[k * HW];
  }

  // ---------------- gather + blend ----------------
  auto gather_store = [&](int buf, int cbase) {
    float acc[8];
#pragma unroll
    for (int i = 0; i < 8; ++i) acc[i] = 0.f;
#pragma unroll
    for (int g = 0; g < 3; ++g) {
      __half2 h[4];  // packed partial, <=3 neighbors before f32 fold
#pragma unroll
      for (int i = 0; i < 4; ++i) h[i] = u2h(0u);
#pragma unroll
      for (int dj = 0; dj < 3; ++dj) {
        const int n = g * 3 + dj;
        const int u00 = u00a[n];
        const __half2 w00 = __half2half2(__low2half(wxa[n]));
        const __half2 w10 = __half2half2(__high2half(wxa[n]));
        const __half2 w01 = __half2half2(__low2half(wya[n]));
        const __half2 w11 = __half2half2(__high2half(wya[n]));
#define CORNER(UIDX, Wh)                          \
  {                                               \
    const uint4 q = lds[buf][(UIDX)];             \
    h[0] = __hfma2(u2h(q.x), (Wh), h[0]);         \
    h[1] = __hfma2(u2h(q.y), (Wh), h[1]);         \
    h[2] = __hfma2(u2h(q.z), (Wh), h[2]);         \
    h[3] = __hfma2(u2h(q.w), (Wh), h[3]);         \
  }
        CORNER(u00, w00)
        CORNER(u00 + 1, w10)
        CORNER(u00 + RCOLS, w01)
        CORNER(u00 + RCOLS + 1, w11)
#undef CORNER
      }
#pragma unroll
      for (int i = 0; i < 4; ++i) {
        const h2r a = __builtin_bit_cast(h2r, h[i]);
        acc[2 * i]     += (float)a.x;
        acc[2 * i + 1] += (float)a.y;
      }
    }
#pragma unroll
    for (int j = 0; j < 8; ++j) out[(cbase + j) * HW + po] = acc[j] * s;
  };

  LBAR();               // buf0 visible; chunk1 loads still in flight
  gather_store(0, 0);   // channels 0..7 (hides chunk1 load latency)

  // fence: keep the pack (and its vm-wait) BELOW gather0 (R9 lesson)
  __builtin_amdgcn_sched_barrier(0);

  // pack + write chunk1 into buf1 (loads are long done by now)
#pragma unroll
  for (int it = 0; it < 5; ++it) {
    const int f = it * 512 + tid;
    if (f < NSLOT) {
      uint4 o;
      o.x = pkrtz_u(r1[it][0], r1[it][1]);
      o.y = pkrtz_u(r1[it][2], r1[it][3]);
      o.z = pkrtz_u(r1[it][4], r1[it][5]);
      o.w = pkrtz_u(r1[it][6], r1[it][7]);
      lds[1][f] = o;
    }
  }

  LBAR();               // buf1 visible
  gather_store(1, 8);   // channels 8..15
}

extern "C" void kernel_launch(void* const* d_in, const int* in_sizes, int n_in,
                              void* d_out, int out_size, void* d_ws, size_t ws_size,
                              hipStream_t stream) {
  const float* right = (const float*)d_in[0];  // [1,16,512,960]
  const float* offx  = (const float*)d_in[1];  // [1,1,512,960]
  const float* offy  = (const float*)d_in[2];  // [1,1,512,960]
  float* out = (float*)d_out;

  const dim3 grid(WW / TC, HH / TR);  // 15 x 64 = 960 blocks
  recon_fused_f16<<<grid, 512, 0, stream>>>(right, offx, offy, out);
}